// Round 1
// baseline (987.052 us; speedup 1.0000x reference)
//
#include <hip/hip_runtime.h>
#include <hip/hip_bf16.h>

#define B_TOK 16384
#define IN_DIM 128
#define D_DIM 512
#define DEPTH 3
#define NEXP 8
#define FF_DIM 2048
#define EH_DIM 256

typedef __attribute__((ext_vector_type(8))) __bf16 bf16x8;
typedef __attribute__((ext_vector_type(4))) float f32x4;
typedef __attribute__((ext_vector_type(4))) unsigned short u16x4;

__device__ __forceinline__ unsigned short f2bf(float f){
    unsigned int u = __float_as_uint(f);
    u += 0x7fffu + ((u >> 16) & 1u);
    return (unsigned short)(u >> 16);
}

__device__ __forceinline__ float geluf(float x){
    return 0.5f * x * (1.0f + erff(x * 0.70710678118654752f));
}

__device__ __forceinline__ void gload_lds16(const void* g, void* l){
    __builtin_amdgcn_global_load_lds((const __attribute__((address_space(1))) unsigned int*)g,
                                     (__attribute__((address_space(3))) unsigned int*)l,
                                     16, 0, 0);
}

// ---------------- weight conversion (straight fp32 -> bf16) ----------------
struct ConvSeg { const float* src; unsigned short* dst; int n4; };
struct ConvArgs { ConvSeg seg[5]; };

__global__ void convert_kernel(ConvArgs a){
    const int stride = gridDim.x * blockDim.x;
    const int tid = blockIdx.x * blockDim.x + threadIdx.x;
    for (int s = 0; s < 5; ++s){
        const f32x4* src = (const f32x4*)a.seg[s].src;
        u16x4* dst = (u16x4*)a.seg[s].dst;
        const int n4 = a.seg[s].n4;
        for (int i = tid; i < n4; i += stride){
            f32x4 v = src[i];
            u16x4 o;
            o[0] = f2bf(v[0]); o[1] = f2bf(v[1]); o[2] = f2bf(v[2]); o[3] = f2bf(v[3]);
            dst[i] = o;
        }
    }
}

// ---------------- weight transpose-convert: src (K,N) fp32 -> dst (N,K) bf16
struct TSeg { const float* src; unsigned short* dst; int K; int N; int tileStart; };
struct TArgs { TSeg seg[23]; };

__global__ void transpose_kernel(TArgs a){
    __shared__ float t[32][33];
    const int tile = blockIdx.x;
    int s = 0;
    #pragma unroll 1
    while (s < 22 && tile >= a.seg[s+1].tileStart) ++s;
    const TSeg sg = a.seg[s];
    const int local = tile - sg.tileStart;
    const int tilesN = sg.N >> 5;
    const int k0 = (local / tilesN) << 5;
    const int n0 = (local % tilesN) << 5;
    const int tx = threadIdx.x & 31;
    const int ty = threadIdx.x >> 5;   // 0..7
    #pragma unroll
    for (int j = 0; j < 4; ++j){
        t[ty + j*8][tx] = sg.src[(size_t)(k0 + ty + j*8) * sg.N + n0 + tx];
    }
    __syncthreads();
    #pragma unroll
    for (int j = 0; j < 4; ++j){
        const int n = ty + j*8;
        sg.dst[(size_t)(n0 + n) * sg.K + k0 + tx] = f2bf(t[tx][n]);
    }
}

// ---------------- GEMM: C(M,N) = A(M,K)bf16 @ Bt(N,K)bf16^T, fused epilogues
#define EPI_BF16 0
#define EPI_BF16_GELU 1
#define EPI_F32_BIAS 2
#define EPI_F32_RESID 3
#define EPI_F32_GATED 4

template<int EPI>
__global__ void __launch_bounds__(256, 2)
gemm_bt(const unsigned short* __restrict__ A, const unsigned short* __restrict__ Bt,
        const float* __restrict__ bias, const float* __restrict__ resid,
        const float* __restrict__ gate, int expert,
        void* __restrict__ out, int M, int N, int K)
{
    __shared__ unsigned short Al[128*64];
    __shared__ unsigned short Bl[128*64];
    const int tid  = threadIdx.x;
    const int lane = tid & 63;
    const int wave = tid >> 6;
    const int wm = (wave >> 1) << 6;
    const int wn = (wave & 1) << 6;
    const int bm = blockIdx.y, bn = blockIdx.x;

    f32x4 acc[4][4] = {};

    const unsigned short* Abase = A + (size_t)bm * 128 * K;
    const unsigned short* Bbase = Bt + (size_t)bn * 128 * K;
    const int soff = tid * 16;

    for (int kt = 0; kt < K; kt += 64){
        #pragma unroll
        for (int s = 0; s < 4; ++s){
            const int off = s*4096 + soff;
            const int row = off >> 7, colb = off & 127;
            gload_lds16((const char*)(Abase + (size_t)row*K + kt) + colb, (char*)Al + off);
        }
        #pragma unroll
        for (int s = 0; s < 4; ++s){
            const int off = s*4096 + soff;
            const int row = off >> 7, colb = off & 127;
            gload_lds16((const char*)(Bbase + (size_t)row*K + kt) + colb, (char*)Bl + off);
        }
        __syncthreads();
        #pragma unroll
        for (int ks = 0; ks < 2; ++ks){
            const int k0 = ks*32 + ((lane>>4)<<3);
            bf16x8 af[4], bfr[4];
            #pragma unroll
            for (int i=0;i<4;i++) af[i]  = *(const bf16x8*)&Al[(wm + i*16 + (lane&15))*64 + k0];
            #pragma unroll
            for (int j=0;j<4;j++) bfr[j] = *(const bf16x8*)&Bl[(wn + j*16 + (lane&15))*64 + k0];
            #pragma unroll
            for (int i=0;i<4;i++)
                #pragma unroll
                for (int j=0;j<4;j++)
                    acc[i][j] = __builtin_amdgcn_mfma_f32_16x16x32_bf16(af[i], bfr[j], acc[i][j], 0, 0, 0);
        }
        __syncthreads();
    }

    const int r0 = ((lane>>4)<<2);
    const int cc = lane & 15;
    #pragma unroll
    for (int j=0;j<4;j++){
        const int col = bn*128 + wn + j*16 + cc;
        const float bv = bias[col];
        #pragma unroll
        for (int i=0;i<4;i++){
            #pragma unroll
            for (int r=0;r<4;r++){
                const int row = bm*128 + wm + i*16 + r0 + r;
                const size_t idx = (size_t)row * N + col;
                float v = acc[i][j][r] + bv;
                if (EPI == EPI_BF16)            ((unsigned short*)out)[idx] = f2bf(v);
                else if (EPI == EPI_BF16_GELU)  ((unsigned short*)out)[idx] = f2bf(geluf(v));
                else if (EPI == EPI_F32_BIAS)   ((float*)out)[idx] = v;
                else if (EPI == EPI_F32_RESID)  ((float*)out)[idx] = resid[idx] + v;
                else                            ((float*)out)[idx] += gate[(size_t)row*NEXP + expert] * v;
            }
        }
    }
}

// ---------------- LayerNorm (fp32 in, bf16 out), one wave per row ----------
__global__ void ln_kernel(const float* __restrict__ x, const float* __restrict__ w,
                          const float* __restrict__ b, unsigned short* __restrict__ out)
{
    const int lane = threadIdx.x & 63;
    const int wave = threadIdx.x >> 6;
    const int row  = blockIdx.x * 4 + wave;
    const float* xr = x + (size_t)row * D_DIM;
    f32x4 v0 = *(const f32x4*)(xr + lane*8);
    f32x4 v1 = *(const f32x4*)(xr + lane*8 + 4);
    float s  = v0[0]+v0[1]+v0[2]+v0[3] + v1[0]+v1[1]+v1[2]+v1[3];
    float s2 = v0[0]*v0[0]+v0[1]*v0[1]+v0[2]*v0[2]+v0[3]*v0[3]
             + v1[0]*v1[0]+v1[1]*v1[1]+v1[2]*v1[2]+v1[3]*v1[3];
    #pragma unroll
    for (int o = 32; o > 0; o >>= 1){ s += __shfl_xor(s, o); s2 += __shfl_xor(s2, o); }
    const float mean = s * (1.0f/512.0f);
    const float var  = s2 * (1.0f/512.0f) - mean*mean;
    const float inv  = 1.0f / sqrtf(var + 1e-5f);
    const int k = lane*8;
    u16x4 o0, o1;
    #pragma unroll
    for (int j=0;j<4;j++) o0[j] = f2bf((v0[j]-mean)*inv*w[k+j]   + b[k+j]);
    #pragma unroll
    for (int j=0;j<4;j++) o1[j] = f2bf((v1[j]-mean)*inv*w[k+4+j] + b[k+4+j]);
    *(u16x4*)(out + (size_t)row*D_DIM + k)     = o0;
    *(u16x4*)(out + (size_t)row*D_DIM + k + 4) = o1;
}

// ---------------- Router: logits, softmax, eps-mix, top-2 gate, prob sums --
__global__ void router_kernel(const float* __restrict__ z, const float* __restrict__ rw,
                              const float* __restrict__ rb, float* __restrict__ gate,
                              float* __restrict__ bsums)
{
    __shared__ float ps[4][8];
    const int lane = threadIdx.x & 63;
    const int wave = threadIdx.x >> 6;
    const int row  = blockIdx.x * 4 + wave;
    const float* zr = z + (size_t)row * D_DIM;
    f32x4 z0 = *(const f32x4*)(zr + lane*8);
    f32x4 z1 = *(const f32x4*)(zr + lane*8 + 4);
    float acc[8] = {0,0,0,0,0,0,0,0};
    #pragma unroll
    for (int j = 0; j < 8; ++j){
        const float zv = (j < 4) ? z0[j] : z1[j-4];
        const float* wr = rw + (size_t)(lane*8 + j) * 8;
        f32x4 w0 = *(const f32x4*)wr;
        f32x4 w1 = *(const f32x4*)(wr + 4);
        acc[0] += zv*w0[0]; acc[1] += zv*w0[1]; acc[2] += zv*w0[2]; acc[3] += zv*w0[3];
        acc[4] += zv*w1[0]; acc[5] += zv*w1[1]; acc[6] += zv*w1[2]; acc[7] += zv*w1[3];
    }
    #pragma unroll
    for (int o = 32; o > 0; o >>= 1){
        #pragma unroll
        for (int e = 0; e < 8; ++e) acc[e] += __shfl_xor(acc[e], o);
    }
    if (lane == 0){
        float p[8]; float mx = -1e30f;
        #pragma unroll
        for (int e=0;e<8;e++){ p[e] = acc[e] + rb[e]; mx = fmaxf(mx, p[e]); }
        float se = 0.f;
        #pragma unroll
        for (int e=0;e<8;e++){ p[e] = expf(p[e]-mx); se += p[e]; }
        const float sc = 0.9f / se;
        #pragma unroll
        for (int e=0;e<8;e++) p[e] = p[e]*sc + 0.0125f;
        int i1 = 0;
        #pragma unroll
        for (int e=1;e<8;e++) if (p[e] > p[i1]) i1 = e;
        int i2 = (i1 == 0) ? 1 : 0;
        for (int e=i2+1;e<8;e++) if (e != i1 && p[e] > p[i2]) i2 = e;
        float* gr = gate + (size_t)row*8;
        #pragma unroll
        for (int e=0;e<8;e++){ gr[e] = (e==i1 || e==i2) ? p[e] : 0.0f; ps[wave][e] = p[e]; }
    }
    __syncthreads();
    if (threadIdx.x < 8){
        bsums[blockIdx.x*8 + threadIdx.x] =
            ps[0][threadIdx.x] + ps[1][threadIdx.x] + ps[2][threadIdx.x] + ps[3][threadIdx.x];
    }
}

// ---------------- aux loss: deterministic reduce of per-block prob sums ----
__global__ void aux_kernel(const float* __restrict__ bsums, float* __restrict__ out_aux)
{
    __shared__ float part[256];
    const int t = threadIdx.x;
    const int e = t & 7, chunk = t >> 3;
    float s = 0.f;
    for (int blk = chunk*128; blk < chunk*128 + 128; ++blk) s += bsums[blk*8 + e];
    part[t] = s;
    __syncthreads();
    if (t < 8){
        float tot = 0.f;
        for (int c = 0; c < 32; ++c) tot += part[c*8 + t];
        part[t] = tot;
    }
    __syncthreads();
    if (t == 0){
        float aux = 0.f;
        for (int e2 = 0; e2 < 8; ++e2){
            float load = part[e2] * (1.0f/16384.0f);
            aux += load * logf(load * 8.0f + 1e-9f);
        }
        out_aux[0] = aux / 2.0794415416798357f;
    }
}

// ---------------- prep for MoE: z -> bf16, and zmoe = z -------------------
__global__ void prep_moe_kernel(const float* __restrict__ h, unsigned short* __restrict__ zbf,
                                float* __restrict__ zmoe)
{
    const int i = blockIdx.x * blockDim.x + threadIdx.x;
    f32x4 v = ((const f32x4*)h)[i];
    u16x4 o; o[0]=f2bf(v[0]); o[1]=f2bf(v[1]); o[2]=f2bf(v[2]); o[3]=f2bf(v[3]);
    ((u16x4*)zbf)[i] = o;
    ((f32x4*)zmoe)[i] = v;
}

// ---------------- head: LN + dot(head_w) + head_b, one wave per row --------
__global__ void head_kernel(const float* __restrict__ z, const float* __restrict__ w,
                            const float* __restrict__ b, const float* __restrict__ hw,
                            const float* __restrict__ hb, float* __restrict__ out)
{
    const int lane = threadIdx.x & 63;
    const int wave = threadIdx.x >> 6;
    const int row  = blockIdx.x * 4 + wave;
    const float* zr = z + (size_t)row * D_DIM;
    f32x4 v0 = *(const f32x4*)(zr + lane*8);
    f32x4 v1 = *(const f32x4*)(zr + lane*8 + 4);
    float s  = v0[0]+v0[1]+v0[2]+v0[3] + v1[0]+v1[1]+v1[2]+v1[3];
    float s2 = v0[0]*v0[0]+v0[1]*v0[1]+v0[2]*v0[2]+v0[3]*v0[3]
             + v1[0]*v1[0]+v1[1]*v1[1]+v1[2]*v1[2]+v1[3]*v1[3];
    #pragma unroll
    for (int o = 32; o > 0; o >>= 1){ s += __shfl_xor(s, o); s2 += __shfl_xor(s2, o); }
    const float mean = s * (1.0f/512.0f);
    const float var  = s2 * (1.0f/512.0f) - mean*mean;
    const float inv  = 1.0f / sqrtf(var + 1e-5f);
    const int k = lane*8;
    float dot = 0.f;
    #pragma unroll
    for (int j=0;j<4;j++) dot += ((v0[j]-mean)*inv*w[k+j]   + b[k+j])   * hw[k+j];
    #pragma unroll
    for (int j=0;j<4;j++) dot += ((v1[j]-mean)*inv*w[k+4+j] + b[k+4+j]) * hw[k+4+j];
    #pragma unroll
    for (int o = 32; o > 0; o >>= 1) dot += __shfl_xor(dot, o);
    if (lane == 0) out[row] = dot + hb[0];
}

// ===========================================================================
extern "C" void kernel_launch(void* const* d_in, const int* in_sizes, int n_in,
                              void* d_out, int out_size, void* d_ws, size_t ws_size,
                              hipStream_t stream)
{
    (void)in_sizes; (void)n_in; (void)out_size; (void)ws_size;
    const float* x         = (const float*)d_in[0];
    const float* embed_w   = (const float*)d_in[1];
    const float* embed_b   = (const float*)d_in[2];
    const float* ln1_w     = (const float*)d_in[3];
    const float* ln1_b     = (const float*)d_in[4];
    const float* inproj_w  = (const float*)d_in[5];
    const float* inproj_b  = (const float*)d_in[6];
    const float* outproj_w = (const float*)d_in[7];
    const float* outproj_b = (const float*)d_in[8];
    const float* ln2_w     = (const float*)d_in[9];
    const float* ln2_b     = (const float*)d_in[10];
    const float* ffn_w1    = (const float*)d_in[11];
    const float* ffn_b1    = (const float*)d_in[12];
    const float* ffn_w2    = (const float*)d_in[13];
    const float* ffn_b2    = (const float*)d_in[14];
    const float* router_w  = (const float*)d_in[15];
    const float* router_b  = (const float*)d_in[16];
    const float* exp_w1    = (const float*)d_in[17];
    const float* exp_b1    = (const float*)d_in[18];
    const float* exp_w2    = (const float*)d_in[19];
    const float* exp_b2    = (const float*)d_in[20];
    const float* head_ln_w = (const float*)d_in[21];
    const float* head_ln_b = (const float*)d_in[22];
    const float* head_w    = (const float*)d_in[23];
    const float* head_b    = (const float*)d_in[24];

    char* ws = (char*)d_ws;
    unsigned short* xbf  = (unsigned short*)(ws + 0);           //  4,194,304
    unsigned short* ebf  = (unsigned short*)(ws + 4194304);     //    131,072  embed_w^T (512,128)
    unsigned short* wvbf = (unsigned short*)(ws + 4325376);     //  1,572,864  inproj V-slices (3,512,512)
    unsigned short* wobf = (unsigned short*)(ws + 5898240);     //  1,572,864  outproj (3,512,512)
    unsigned short* w1t  = (unsigned short*)(ws + 7471104);     //  6,291,456  ffn_w1^T (3,2048,512)
    unsigned short* w2t  = (unsigned short*)(ws + 13762560);    //  6,291,456  ffn_w2^T (3,512,2048)
    unsigned short* e1t  = (unsigned short*)(ws + 20054016);    //  2,097,152  exp_w1^T (8,256,512)
    unsigned short* e2t  = (unsigned short*)(ws + 22151168);    //  2,097,152  exp_w2^T (8,512,256)
    float*          h    = (float*)(ws + 24248320);             // 33,554,432
    unsigned short* gbf  = (unsigned short*)(ws + 57802752);    // 16,777,216  (also zbf)
    unsigned short* vbf  = (unsigned short*)(ws + 74579968);    // 16,777,216  (also hmid)
    unsigned short* ubf  = (unsigned short*)(ws + 91357184);    // 67,108,864  (also zmoe fp32)
    float*          gate = (float*)(ws + 158466048);            //    524,288
    float*          bsums= (float*)(ws + 158990336);            //    131,072
    unsigned short* zbf  = gbf;
    unsigned short* hmid = vbf;
    float*          zmoe = (float*)ubf;
    float*          out  = (float*)d_out;

    // ---- weight prep ----
    ConvArgs ca;
    ca.seg[0] = { x, xbf, B_TOK*IN_DIM/4 };
    for (int l = 0; l < DEPTH; ++l)
        ca.seg[1+l] = { inproj_w + (size_t)l*3*D_DIM*D_DIM + 2*D_DIM*D_DIM,
                        wvbf + (size_t)l*D_DIM*D_DIM, D_DIM*D_DIM/4 };
    ca.seg[4] = { outproj_w, wobf, DEPTH*D_DIM*D_DIM/4 };
    convert_kernel<<<1024, 256, 0, stream>>>(ca);

    TArgs ta;
    int tcur = 0, ti = 0;
    {
        ta.seg[ti] = { embed_w, ebf, IN_DIM, D_DIM, tcur };
        tcur += (IN_DIM/32)*(D_DIM/32); ++ti;
        for (int l = 0; l < DEPTH; ++l){
            ta.seg[ti] = { ffn_w1 + (size_t)l*D_DIM*FF_DIM, w1t + (size_t)l*FF_DIM*D_DIM, D_DIM, FF_DIM, tcur };
            tcur += (D_DIM/32)*(FF_DIM/32); ++ti;
        }
        for (int l = 0; l < DEPTH; ++l){
            ta.seg[ti] = { ffn_w2 + (size_t)l*FF_DIM*D_DIM, w2t + (size_t)l*D_DIM*FF_DIM, FF_DIM, D_DIM, tcur };
            tcur += (FF_DIM/32)*(D_DIM/32); ++ti;
        }
        for (int e = 0; e < NEXP; ++e){
            ta.seg[ti] = { exp_w1 + (size_t)e*D_DIM*EH_DIM, e1t + (size_t)e*EH_DIM*D_DIM, D_DIM, EH_DIM, tcur };
            tcur += (D_DIM/32)*(EH_DIM/32); ++ti;
        }
        for (int e = 0; e < NEXP; ++e){
            ta.seg[ti] = { exp_w2 + (size_t)e*EH_DIM*D_DIM, e2t + (size_t)e*D_DIM*EH_DIM, EH_DIM, D_DIM, tcur };
            tcur += (EH_DIM/32)*(D_DIM/32); ++ti;
        }
    }
    transpose_kernel<<<tcur, 256, 0, stream>>>(ta);

    const dim3 blk(256);
    // embed: h = x @ embed_w + embed_b
    gemm_bt<EPI_F32_BIAS><<<dim3(D_DIM/128, B_TOK/128), blk, 0, stream>>>(
        xbf, ebf, embed_b, nullptr, nullptr, 0, h, B_TOK, D_DIM, IN_DIM);

    for (int l = 0; l < DEPTH; ++l){
        ln_kernel<<<B_TOK/4, 256, 0, stream>>>(h, ln1_w + l*D_DIM, ln1_b + l*D_DIM, gbf);
        gemm_bt<EPI_BF16><<<dim3(D_DIM/128, B_TOK/128), blk, 0, stream>>>(
            gbf, wvbf + (size_t)l*D_DIM*D_DIM, inproj_b + l*3*D_DIM + 2*D_DIM,
            nullptr, nullptr, 0, vbf, B_TOK, D_DIM, D_DIM);
        gemm_bt<EPI_F32_RESID><<<dim3(D_DIM/128, B_TOK/128), blk, 0, stream>>>(
            vbf, wobf + (size_t)l*D_DIM*D_DIM, outproj_b + l*D_DIM,
            h, nullptr, 0, h, B_TOK, D_DIM, D_DIM);
        ln_kernel<<<B_TOK/4, 256, 0, stream>>>(h, ln2_w + l*D_DIM, ln2_b + l*D_DIM, gbf);
        gemm_bt<EPI_BF16_GELU><<<dim3(FF_DIM/128, B_TOK/128), blk, 0, stream>>>(
            gbf, w1t + (size_t)l*FF_DIM*D_DIM, ffn_b1 + l*FF_DIM,
            nullptr, nullptr, 0, ubf, B_TOK, FF_DIM, D_DIM);
        gemm_bt<EPI_F32_RESID><<<dim3(D_DIM/128, B_TOK/128), blk, 0, stream>>>(
            ubf, w2t + (size_t)l*D_DIM*FF_DIM, ffn_b2 + l*D_DIM,
            h, nullptr, 0, h, B_TOK, D_DIM, FF_DIM);
    }

    router_kernel<<<B_TOK/4, 256, 0, stream>>>(h, router_w, router_b, gate, bsums);
    aux_kernel<<<1, 256, 0, stream>>>(bsums, out + B_TOK);
    prep_moe_kernel<<<B_TOK*D_DIM/4/256, 256, 0, stream>>>(h, zbf, zmoe);

    for (int e = 0; e < NEXP; ++e){
        gemm_bt<EPI_BF16_GELU><<<dim3(EH_DIM/128, B_TOK/128), blk, 0, stream>>>(
            zbf, e1t + (size_t)e*EH_DIM*D_DIM, exp_b1 + e*EH_DIM,
            nullptr, nullptr, 0, hmid, B_TOK, EH_DIM, D_DIM);
        gemm_bt<EPI_F32_GATED><<<dim3(D_DIM/128, B_TOK/128), blk, 0, stream>>>(
            hmid, e2t + (size_t)e*D_DIM*EH_DIM, exp_b2 + e*D_DIM,
            nullptr, gate, e, zmoe, B_TOK, D_DIM, EH_DIM);
    }

    head_kernel<<<B_TOK/4, 256, 0, stream>>>(zmoe, head_ln_w, head_ln_b, head_w, head_b, out);
}